// Round 5
// baseline (456.259 us; speedup 1.0000x reference)
//
#include <hip/hip_runtime.h>
#include <math.h>

typedef unsigned int u32;
typedef unsigned long long u64;

#define NANCH   36864
#define PRE     6000
#define POST    2000
#define NWORDS  94        // ceil(6000/64)

// ---------------- workspace layout (bytes) ----------------
#define OFF_PROPS   ((size_t)0)                    // 36864 * 16 = 589824
#define OFF_SV      ((size_t)589824)               // 36864 * 8  = 294912
#define OFF_TOPBOX  ((size_t)884736)               // 6016 * 16  = 96256
#define OFF_SORTED  ((size_t)980992)               // 6016 * 8   = 48128
#define OFF_SEL     ((size_t)1029120)              // 6016 * 8   = 48128
#define OFF_TOPKEY  ((size_t)1077248)              // 6016 * 4   = 24064
#define OFF_INVALW  ((size_t)1101312)              // 94 * 8 -> pad 768 (16B aligned)
#define OFF_MASK    ((size_t)1102080)              // 6000 * 94 * 8 = 4512000 (16B aligned)
#define OFF_ZERO    ((size_t)5614080)              // zeroed region start
#define OFF_H1      (OFF_ZERO)                     // 65536 * 4
#define OFF_H2      (OFF_H1 + 262144)
#define OFF_H3      (OFF_H2 + 262144)
#define OFF_CTRL    (OFF_H3 + 262144)              // 256 B: u32[0..7] + u64 T at +32
#define OFF_KEEPW   (OFF_CTRL + 256)               // 94*8 -> pad 768
#define OFF_RANK    (OFF_KEEPW + 768)              // 6016 * 4 = 24064
#define ZERO_BYTES  ((size_t)(262144*3 + 256 + 768 + 24064))

// base anchors for base_size=16, ratios(0.5,1,2), scales(8,16,32) — np.round (banker's) applied
__device__ __constant__ float BA[9][4] = {
  {-84.f,-40.f,99.f,55.f},   {-176.f,-88.f,191.f,103.f}, {-360.f,-184.f,375.f,199.f},
  {-56.f,-56.f,71.f,71.f},   {-120.f,-120.f,135.f,135.f},{-248.f,-248.f,263.f,263.f},
  {-36.f,-80.f,51.f,95.f},   {-80.f,-168.f,95.f,183.f},  {-168.f,-344.f,183.f,359.f}};

// ---------------- 1) decode (+ fused level-1 histogram) ----------------
__global__ void decode_k(const float* __restrict__ deltas, const float* __restrict__ scores,
                         const int* __restrict__ imw_p, const int* __restrict__ imh_p,
                         float4* __restrict__ props, u64* __restrict__ sortvals,
                         u32* __restrict__ h1) {
  #pragma clang fp contract(off)
  int i = blockIdx.x * 256 + threadIdx.x;
  if (i >= NANCH) return;
  int a = i % 9;
  int pix = i / 9;
  int x = pix & 63, y = pix >> 6;

  float sc = scores[(9 + a) * 4096 + pix];
  float d0 = deltas[(a * 4 + 0) * 4096 + pix];
  float d1 = deltas[(a * 4 + 1) * 4096 + pix];
  float d2 = deltas[(a * 4 + 2) * 4096 + pix];
  float d3 = deltas[(a * 4 + 3) * 4096 + pix];

  float gx = (float)(x * 16), gy = (float)(y * 16);
  float ax1 = gx + BA[a][0], ay1 = gy + BA[a][1];
  float ax2 = gx + BA[a][2], ay2 = gy + BA[a][3];
  float aw = ax2 - ax1 + 1.0f, ah = ay2 - ay1 + 1.0f;
  float acx = ax1 + 0.5f * aw, acy = ay1 + 0.5f * ah;

  float pcx = d0 * aw + acx;
  float pcy = d1 * ah + acy;
  float pw = (float)exp((double)d2) * aw;   // f64 exp -> correctly-rounded f32
  float ph = (float)exp((double)d3) * ah;

  float imw1 = (float)imw_p[0] - 1.0f, imh1 = (float)imh_p[0] - 1.0f;
  float x1 = fminf(fmaxf(pcx - 0.5f * pw, 0.0f), imw1);
  float y1 = fminf(fmaxf(pcy - 0.5f * ph, 0.0f), imh1);
  float x2 = fminf(fmaxf(pcx + 0.5f * pw, 0.0f), imw1);
  float y2 = fminf(fmaxf(pcy + 0.5f * ph, 0.0f), imh1);
  props[i] = make_float4(x1, y1, x2, y2);

  float thresh = 16.0f * ((float)imh_p[0] / (float)imw_p[0]);
  bool keep = (x2 - x1 + 1.0f >= thresh) && (y2 - y1 + 1.0f >= thresh);
  u32 key = keep ? (__float_as_uint(sc) | 0x80000000u) : 0u;  // scores >= 0
  sortvals[i] = ((u64)key << 32) | (u64)(0xFFFFFFFFu - (u32)i); // distinct; desc order == top_k order
  atomicAdd(&h1[key >> 16], 1u);                               // fused level-1 histogram
}

// ---------------- 2) exact top-6000 threshold via 3-level radix histogram ----------------
__global__ void hist_k(const u64* __restrict__ sv, u32* __restrict__ hist,
                       const u32* __restrict__ ctrl, int level) {
  int i = blockIdx.x * 256 + threadIdx.x;
  if (i >= NANCH) return;
  u64 v = sv[i];
  if (level == 2) {
    if ((u32)(v >> 48) == ctrl[0]) atomicAdd(&hist[(u32)(v >> 32) & 0xFFFFu], 1u);
  } else {
    u32 pfx = (ctrl[0] << 16) | ctrl[2];
    if ((u32)(v >> 32) == pfx) atomicAdd(&hist[(u32)v & 0xFFFFu], 1u);
  }
}

// Parallel suffix-select: find largest bucket with suffix-count >= Rin.
// Hierarchy: 1024 groups of 64 bins; per-wave coalesced group sums,
// wave-shfl suffix scans, single crossing thread -> bin-level in wave 0.
__global__ void __launch_bounds__(1024) scan_k(const u32* __restrict__ hist,
                                               u32* __restrict__ ctrl, int level) {
  __shared__ u32 part[1024];
  __shared__ u32 wtot[16], wsfx[16];
  __shared__ int cgrp;
  __shared__ u32 ghi;
  const int t = threadIdx.x, w = t >> 6, l = t & 63;

  // group sums: wave w handles groups g = w + 16k, lanes read 64 bins coalesced
  for (int k = 0; k < 64; ++k) {
    int gg = w + (k << 4);
    u32 v = hist[gg * 64 + l];
    for (int off = 32; off; off >>= 1) v += __shfl_down(v, off);
    if (l == 0) part[gg] = v;
  }
  __syncthreads();

  // inclusive suffix scan within wave over part[w*64 + l]
  u32 v = part[t];
  for (int off = 1; off < 64; off <<= 1) {
    u32 o = __shfl_down(v, off);
    if (l + off < 64) v += o;
  }
  if (l == 0) wtot[w] = v;
  __syncthreads();
  if (w == 0 && l < 16) {
    u32 x = wtot[l];
    for (int off = 1; off < 16; off <<= 1) {
      u32 o = __shfl_down(x, off);
      if (l + off < 16) x += o;
    }
    wsfx[l] = x;           // sum of wave totals w' >= l
  }
  __syncthreads();

  u32 Rin = (level == 1) ? (u32)PRE : ctrl[(level - 1) * 2 - 1];
  u32 G = v + ((w < 15) ? wsfx[w + 1] : 0);   // suffix count from group t
  u32 p = part[t];
  if (G >= Rin && G - p < Rin) { cgrp = t; ghi = G - p; }  // unique crossing
  __syncthreads();

  if (w == 0) {
    int gg = cgrp;
    u32 h = hist[gg * 64 + l];
    u32 s = h;
    for (int off = 1; off < 64; off <<= 1) {
      u32 o = __shfl_down(s, off);
      if (l + off < 64) s += o;
    }
    u32 S = s + ghi;                       // suffix count from bin gg*64+l
    u64 m = __ballot(S >= Rin);
    int cb = 63 - __builtin_clzll(m);      // largest bin with S >= Rin
    if (l == cb) {
      u32 Rout = Rin - (S - h);
      int chosen = gg * 64 + cb;
      ctrl[(level - 1) * 2] = (u32)chosen;
      ctrl[(level - 1) * 2 + 1] = Rout;
      if (level == 3) {
        // bits 16..31 of every sortval are 0xFFFF (idx < 65536)
        u64 T = ((u64)ctrl[0] << 48) | ((u64)ctrl[2] << 32) | 0xFFFF0000ULL | (u64)(u32)chosen;
        *(u64*)(&ctrl[8]) = T;   // exactly 6000 sortvals are >= T (all distinct)
      }
    }
  }
}

__global__ void compact_k(const u64* __restrict__ sv, u32* __restrict__ ctrl,
                          u64* __restrict__ sel) {
  int i = blockIdx.x * 256 + threadIdx.x;
  if (i >= NANCH) return;
  u64 T = *(const u64*)(&ctrl[8]);
  u64 v = sv[i];
  if (v >= T) {
    u32 p = atomicAdd(&ctrl[6], 1u);
    sel[p] = v;
  }
}

// ---------------- 3) sort via all-pairs rank (keys are all distinct) ----------------
#define JCHUNK 1500
__global__ void rank_k(const u64* __restrict__ sel, u32* __restrict__ rank) {
  __shared__ u64 sj[256];
  int i = blockIdx.x * 256 + threadIdx.x;
  u64 vi = (i < PRE) ? sel[i] : 0ULL;
  int j0 = blockIdx.y * JCHUNK;
  int j1 = min(j0 + JCHUNK, PRE);
  u32 cnt = 0;
  for (int jb = j0; jb < j1; jb += 256) {
    int nj = min(256, j1 - jb);
    __syncthreads();
    if (threadIdx.x < nj) sj[threadIdx.x] = sel[jb + threadIdx.x];
    __syncthreads();
    #pragma unroll 8
    for (int j = 0; j < nj; ++j) cnt += (u32)(sj[j] > vi);
  }
  if (i < PRE && cnt) atomicAdd(&rank[i], cnt);
}

__global__ void rankscatter_k(const u64* __restrict__ sel, const u32* __restrict__ rank,
                              u64* __restrict__ sorted) {
  int i = blockIdx.x * 256 + threadIdx.x;
  if (i < PRE) sorted[rank[i]] = sel[i];
}

// ---------------- 4) gather boxes/keys; build invalid-bit words ----------------
__global__ void gather_k(const u64* __restrict__ sorted, const float4* __restrict__ props,
                         float4* __restrict__ topbox, u32* __restrict__ topkey,
                         u64* __restrict__ invalw) {
  int r = blockIdx.x * 64 + threadIdx.x;
  u32 key = 0;
  if (r < PRE) {
    u64 v = sorted[r];
    key = (u32)(v >> 32);
    u32 idx = 0xFFFFu - ((u32)v & 0xFFFFu);
    topbox[r] = props[idx];
    topkey[r] = key;
  }
  u64 inval = __ballot(key == 0u);
  if (threadIdx.x == 0) invalw[blockIdx.x] = inval;
}

// ---------------- 5) suppression bitmask: upper-triangle 64x64 tiles ----------------
__global__ void mask_k(const float4* __restrict__ topbox, u64* __restrict__ mask) {
  #pragma clang fp contract(off)
  __shared__ float4 cb[64];
  int jb = blockIdx.x;
  if (jb < (int)blockIdx.y) return;   // only w >= row-block is ever read
  int i = blockIdx.y * 64 + threadIdx.x;
  int jj = jb * 64 + threadIdx.x;
  cb[threadIdx.x] = (jj < PRE) ? topbox[jj] : make_float4(0.f, 0.f, 0.f, 0.f);
  __syncthreads();
  if (i >= PRE) return;
  float4 b = topbox[i];
  float ai = (b.z - b.x + 1.0f) * (b.w - b.y + 1.0f);
  u64 bits = 0ULL;
  int jmax = min(64, PRE - jb * 64);
  for (int j = 0; j < jmax; ++j) {
    float4 c = cb[j];
    float aj = (c.z - c.x + 1.0f) * (c.w - c.y + 1.0f);
    float iw = fmaxf(fminf(b.z, c.z) - fmaxf(b.x, c.x) + 1.0f, 0.0f);
    float ih = fmaxf(fminf(b.w, c.w) - fmaxf(b.y, c.y) + 1.0f, 0.0f);
    float inter = iw * ih;
    float iou = inter / (ai + aj - inter);
    bits |= ((u64)(iou > 0.7f)) << j;
  }
  mask[(size_t)i * NWORDS + jb] = bits;
}

// ---------------- 6) block-parallel greedy scan ----------------
// Lightweight barrier: drain LDS ops only — does NOT drain vmcnt, so the
// global prefetch stays in flight across steps (the __syncthreads vmcnt(0)
// drain was the 122us bottleneck). Correctness: cross-thread data passes
// only through LDS (lgkmcnt-drained); B-buffers are thread-private and get
// compiler-inserted vmcnt(N) waits at their actual use.
__device__ __forceinline__ void wg_barrier() {
  __asm__ volatile("s_waitcnt lgkmcnt(0)\n\ts_barrier" ::: "memory");
}
__device__ __forceinline__ u64 rl64(u64 v, int lane) {
  u32 lo = (u32)__builtin_amdgcn_readlane((int)(u32)v, lane);
  u32 hi = (u32)__builtin_amdgcn_readlane((int)(u32)(v >> 32), lane);
  return ((u64)hi << 32) | (u64)lo;
}
__device__ __forceinline__ u64 rfl64(u64 v) {
  u32 lo = (u32)__builtin_amdgcn_readfirstlane((int)(u32)v);
  u32 hi = (u32)__builtin_amdgcn_readfirstlane((int)(u32)(v >> 32));
  return ((u64)hi << 32) | (u64)lo;
}

__global__ void __launch_bounds__(1024) nms_scan_k(const u64* __restrict__ mask,
                                                   const u64* __restrict__ invalw,
                                                   u64* __restrict__ keepw) {
  __shared__ u64 Lrem[NWORDS];
  __shared__ u64 Ldiag[64];
  __shared__ u64 Lkeep;
  __shared__ int Lstop;
  const int t = threadIdx.x;
  const int g = t >> 7;                 // 8 groups of 128 threads
  const int w = t & 127;                // word owned (if < 94)
  const bool loader = (w < NWORDS);
  if (t < NWORDS) Lrem[t] = invalw[t];
  if (t == 0) Lstop = 0;
  u64 rv = 0;                           // group-partial remv for word w
  u64 B0[8], B1[8], B2[8], B3[8];
  int kept = 0;

#define ISSUE(bb, BUF) \
  if ((bb) < NWORDS && loader) { \
    const int row0_ = (bb) * 64 + g * 8; \
    const u64* pp_ = mask + (size_t)row0_ * NWORDS + w; \
    _Pragma("unroll") \
    for (int j = 0; j < 8; ++j) { \
      bool ok_ = (w >= (bb)) && (row0_ + j < PRE); \
      BUF[j] = ok_ ? pp_[(size_t)j * NWORDS] : 0ULL; \
    } \
  }

#define STEP(bb, BUF, BUFN) { \
    if (w == (bb)) {                     /* 8 publishers (one per group) */ \
      atomicOr((u32*)&Lrem[(bb)], (u32)rv); \
      atomicOr(((u32*)&Lrem[(bb)]) + 1, (u32)(rv >> 32)); \
      _Pragma("unroll") \
      for (int j = 0; j < 8; ++j) Ldiag[g * 8 + j] = BUF[j]; \
    } \
    wg_barrier();                        /* X: diag + Lrem[b] visible */ \
    ISSUE((bb) + 3, BUFN)                /* depth-3 prefetch, stays in flight */ \
    if (t < 64) { \
      u64 dgl = Ldiag[t]; \
      u64 avail = ~rfl64(Lrem[(bb)]);    /* keepable rows in this word */ \
      u64 kb = 0; \
      while (avail) { \
        int i_ = __builtin_ctzll(avail); \
        kb |= 1ULL << i_; \
        u64 di_ = rl64(dgl, i_); \
        avail &= ~di_ & ~((2ULL << i_) - 1ULL); /* 2<<63 wraps to 0 -> ~(-1)=0 */ \
      } \
      if (t == 0) { \
        keepw[(bb)] = kb; \
        Lkeep = kb; \
        kept += (int)__popcll(kb); \
        if (kept >= POST) Lstop = 1; \
      } \
    } \
    wg_barrier();                        /* Y: kb + stop visible */ \
    { \
      u64 kb_ = Lkeep; \
      const int base_ = g * 8; \
      _Pragma("unroll") \
      for (int j = 0; j < 8; ++j) { \
        u64 k_ = (kb_ >> (base_ + j)) & 1ULL; \
        rv |= (0ULL - k_) & BUF[j]; \
      } \
    } \
    if (Lstop) break; }

  ISSUE(0, B0)
  ISSUE(1, B1)
  ISSUE(2, B2)
  for (int bb = 0; bb < NWORDS; bb += 4) {
    STEP(bb, B0, B3)
    if (bb + 1 < NWORDS) STEP(bb + 1, B1, B0)
    if (bb + 2 < NWORDS) STEP(bb + 2, B2, B1)
    if (bb + 3 < NWORDS) STEP(bb + 3, B3, B2)
  }
#undef ISSUE
#undef STEP
}

// ---------------- 7) rank + scatter outputs ----------------
__global__ void scatter_k(const u64* __restrict__ keepw, const float4* __restrict__ topbox,
                          const u32* __restrict__ topkey, float* __restrict__ out) {
  __shared__ u64 wl[NWORDS];
  __shared__ u32 pre[NWORDS];
  int t = threadIdx.x;
  if (t < NWORDS) wl[t] = keepw[t];
  __syncthreads();
  if (t == 0) {
    u32 run = 0;
    for (int w = 0; w < NWORDS; ++w) { pre[w] = run; run += (u32)__popcll(wl[w]); }
  }
  __syncthreads();
  for (int i = t; i < PRE; i += 1024) {
    int w = i >> 6;
    u64 word = wl[w];
    if ((word >> (i & 63)) & 1ULL) {
      u32 rank = pre[w] + (u32)__popcll(word & ((1ULL << (i & 63)) - 1ULL));
      if (rank < POST) {
        float4 b = topbox[i];
        out[rank * 5 + 1] = b.x;
        out[rank * 5 + 2] = b.y;
        out[rank * 5 + 3] = b.z;
        out[rank * 5 + 4] = b.w;
        out[10000 + rank] = __uint_as_float(topkey[i] & 0x7FFFFFFFu);  // col 0 stays 0
      }
    }
  }
}

extern "C" void kernel_launch(void* const* d_in, const int* in_sizes, int n_in,
                              void* d_out, int out_size, void* d_ws, size_t ws_size,
                              hipStream_t stream) {
  const float* deltas = (const float*)d_in[0];
  const float* scores = (const float*)d_in[1];
  const int* imw = (const int*)d_in[2];
  const int* imh = (const int*)d_in[3];
  char* ws = (char*)d_ws;

  float4* props   = (float4*)(ws + OFF_PROPS);
  u64*    svals   = (u64*)(ws + OFF_SV);
  float4* topbox  = (float4*)(ws + OFF_TOPBOX);
  u64*    sorted  = (u64*)(ws + OFF_SORTED);
  u64*    sel     = (u64*)(ws + OFF_SEL);
  u32*    topkey  = (u32*)(ws + OFF_TOPKEY);
  u64*    invalw  = (u64*)(ws + OFF_INVALW);
  u64*    maskb   = (u64*)(ws + OFF_MASK);
  u32*    h1      = (u32*)(ws + OFF_H1);
  u32*    h2      = (u32*)(ws + OFF_H2);
  u32*    h3      = (u32*)(ws + OFF_H3);
  u32*    ctrl    = (u32*)(ws + OFF_CTRL);
  u64*    keepw   = (u64*)(ws + OFF_KEEPW);
  u32*    rankb   = (u32*)(ws + OFF_RANK);

  hipMemsetAsync(ws + OFF_ZERO, 0, ZERO_BYTES, stream);      // hists + ctrl + keepwords + rank
  hipMemsetAsync(d_out, 0, 12000 * sizeof(float), stream);   // blob + scores zero-padded

  decode_k<<<144, 256, 0, stream>>>(deltas, scores, imw, imh, props, svals, h1);
  scan_k<<<1, 1024, 0, stream>>>(h1, ctrl, 1);
  hist_k<<<144, 256, 0, stream>>>(svals, h2, ctrl, 2);
  scan_k<<<1, 1024, 0, stream>>>(h2, ctrl, 2);
  hist_k<<<144, 256, 0, stream>>>(svals, h3, ctrl, 3);
  scan_k<<<1, 1024, 0, stream>>>(h3, ctrl, 3);

  compact_k<<<144, 256, 0, stream>>>(svals, ctrl, sel);

  dim3 rgrid(24, 4);
  rank_k<<<rgrid, 256, 0, stream>>>(sel, rankb);
  rankscatter_k<<<24, 256, 0, stream>>>(sel, rankb, sorted);

  gather_k<<<94, 64, 0, stream>>>(sorted, props, topbox, topkey, invalw);

  dim3 mgrid(NWORDS, NWORDS);
  mask_k<<<mgrid, 64, 0, stream>>>(topbox, maskb);

  nms_scan_k<<<1, 1024, 0, stream>>>(maskb, invalw, keepw);
  scatter_k<<<1, 1024, 0, stream>>>(keepw, topbox, topkey, (float*)d_out);
}

// Round 6
// 334.591 us; speedup vs baseline: 1.3636x; 1.3636x over previous
//
#include <hip/hip_runtime.h>
#include <math.h>

typedef unsigned int u32;
typedef unsigned long long u64;

#define NANCH   36864
#define PRE     6000
#define POST    2000
#define NWORDS  94        // ceil(6000/64)

// ---------------- workspace layout (bytes) ----------------
#define OFF_PROPS   ((size_t)0)                    // 36864 * 16 = 589824
#define OFF_SV      ((size_t)589824)               // 36864 * 8  = 294912 -> end 884736
#define OFF_SORTED  ((size_t)884736)               // 6016 * 8   = 48128  -> end 932864
#define OFF_SEL     ((size_t)932864)               // 36864 * 8  = 294912 (fallback-sized) -> end 1227776
#define OFF_MASK    ((size_t)1227776)              // 6000 * 94 * 8 = 4512000 -> end 5739776
#define OFF_CTRL    ((size_t)5739776)              // 256 B
#define OFF_H1      ((size_t)5740032)              // 1025*4 -> pad 4352 -> end 5744384
#define OFF_INVALW  ((size_t)5744384)              // 94*8 -> pad 768 -> end 5745152
#define OFF_KEEPW   ((size_t)5745152)              // 94*8 -> pad 768 (NOT in memset; nms zero-fills tail)
#define ZERO_BYTES  ((size_t)(256 + 4352 + 768))   // ctrl + h1 + invalw

// base anchors for base_size=16, ratios(0.5,1,2), scales(8,16,32) — np.round (banker's) applied
__device__ __constant__ float BA[9][4] = {
  {-84.f,-40.f,99.f,55.f},   {-176.f,-88.f,191.f,103.f}, {-360.f,-184.f,375.f,199.f},
  {-56.f,-56.f,71.f,71.f},   {-120.f,-120.f,135.f,135.f},{-248.f,-248.f,263.f,263.f},
  {-36.f,-80.f,51.f,95.f},   {-80.f,-168.f,95.f,183.f},  {-168.f,-344.f,183.f,359.f}};

// bin over key bits [31:13]: 1024 bins cover scores [0.5,1) exactly (monotone in key);
// bin 0 = everything below (incl. invalid key==0). Selection stays EXACT: we take the
// whole union of bins >= chosen and rank it all-pairs (keys are distinct).
__device__ __forceinline__ u32 key_bin(u32 key) {
  if (key < 0xBF000000u) return 0u;
  u32 b = ((key >> 13) - 0x5F800u) + 1u;
  return b > 1024u ? 1024u : b;
}

// ---------------- 1) decode (+ fused 1024-bin histogram; bin 0 not counted) ----------------
__global__ void decode_k(const float* __restrict__ deltas, const float* __restrict__ scores,
                         const int* __restrict__ imw_p, const int* __restrict__ imh_p,
                         float4* __restrict__ props, u64* __restrict__ sortvals,
                         u32* __restrict__ h1) {
  #pragma clang fp contract(off)
  int i = blockIdx.x * 256 + threadIdx.x;
  if (i >= NANCH) return;
  int a = i % 9;
  int pix = i / 9;
  int x = pix & 63, y = pix >> 6;

  float sc = scores[(9 + a) * 4096 + pix];
  float d0 = deltas[(a * 4 + 0) * 4096 + pix];
  float d1 = deltas[(a * 4 + 1) * 4096 + pix];
  float d2 = deltas[(a * 4 + 2) * 4096 + pix];
  float d3 = deltas[(a * 4 + 3) * 4096 + pix];

  float gx = (float)(x * 16), gy = (float)(y * 16);
  float ax1 = gx + BA[a][0], ay1 = gy + BA[a][1];
  float ax2 = gx + BA[a][2], ay2 = gy + BA[a][3];
  float aw = ax2 - ax1 + 1.0f, ah = ay2 - ay1 + 1.0f;
  float acx = ax1 + 0.5f * aw, acy = ay1 + 0.5f * ah;

  float pcx = d0 * aw + acx;
  float pcy = d1 * ah + acy;
  float pw = (float)exp((double)d2) * aw;   // f64 exp -> correctly-rounded f32
  float ph = (float)exp((double)d3) * ah;

  float imw1 = (float)imw_p[0] - 1.0f, imh1 = (float)imh_p[0] - 1.0f;
  float x1 = fminf(fmaxf(pcx - 0.5f * pw, 0.0f), imw1);
  float y1 = fminf(fmaxf(pcy - 0.5f * ph, 0.0f), imh1);
  float x2 = fminf(fmaxf(pcx + 0.5f * pw, 0.0f), imw1);
  float y2 = fminf(fmaxf(pcy + 0.5f * ph, 0.0f), imh1);
  props[i] = make_float4(x1, y1, x2, y2);

  float thresh = 16.0f * ((float)imh_p[0] / (float)imw_p[0]);
  bool keep = (x2 - x1 + 1.0f >= thresh) && (y2 - y1 + 1.0f >= thresh);
  u32 key = keep ? (__float_as_uint(sc) | 0x80000000u) : 0u;  // scores >= 0
  sortvals[i] = ((u64)key << 32) | (u64)(0xFFFFFFFFu - (u32)i); // distinct; desc order == top_k order
  u32 bin = key_bin(key);
  if (bin) atomicAdd(&h1[bin], 1u);
}

// ---------------- 2) pick chosen bin: largest c>=1 with suffix(c) >= PRE (else 0) ----------------
__global__ void scan_k(const u32* __restrict__ h1, u32* __restrict__ ctrl) {
  int l = threadIdx.x;                 // 64 lanes; lane l owns bins [1+16l, 16l+16]
  u32 loc[16], suf[16];
  #pragma unroll
  for (int k = 0; k < 16; ++k) loc[k] = h1[1 + l * 16 + k];
  u32 acc = 0;
  #pragma unroll
  for (int k = 15; k >= 0; --k) { acc += loc[k]; suf[k] = acc; }
  u32 sfx = acc;                       // suffix over lane totals (l'>=l)
  for (int off = 1; off < 64; off <<= 1) {
    u32 o = __shfl_down(sfx, off);
    if (l + off < 64) sfx += o;
  }
  u32 S_above = sfx - acc;             // sum over lanes > l
  u64 mball = __ballot(suf[0] + S_above >= (u32)PRE);
  if (mball == 0ULL) { if (l == 0) ctrl[0] = 0u; return; }   // fallback: union = everything
  int L = 63 - __builtin_clzll(mball);
  if (l == L) {
    int kk = 0;
    for (int k = 15; k >= 0; --k)
      if (suf[k] + S_above >= (u32)PRE) { kk = k; break; }
    ctrl[0] = (u32)(1 + 16 * L + kk);
  }
}

// ---------------- 3) compact the union (bins >= chosen); order arbitrary ----------------
__global__ void compact_k(const u64* __restrict__ sv, u32* __restrict__ ctrl,
                          u64* __restrict__ sel) {
  int i = blockIdx.x * 256 + threadIdx.x;
  if (i >= NANCH) return;
  u32 chosen = ctrl[0];
  u64 v = sv[i];
  if (key_bin((u32)(v >> 32)) >= chosen) {
    u32 p = atomicAdd(&ctrl[6], 1u);
    sel[p] = v;
  }
}

// ---------------- 4) all-pairs rank of the union -> exact descending sort of top-PRE ----------
// rank(v) = #{u in union : u > v}; union contains the global top-PRE, so ranks < PRE are
// global ranks. Also marks invalid rows (key==0; only possible in fallback) in invalw.
__global__ void rank_k(const u64* __restrict__ sel, const u32* __restrict__ ctrl,
                       u64* __restrict__ sorted, u64* __restrict__ invalw) {
  __shared__ u64 sj[256];
  u32 n = ctrl[6];
  int i = blockIdx.x * 256 + threadIdx.x;
  if ((u32)(blockIdx.x * 256) >= n) return;       // uniform per block
  u64 vi = ((u32)i < n) ? sel[i] : 0ULL;
  u32 cnt = 0;
  for (u32 jb = 0; jb < n; jb += 256) {
    __syncthreads();
    if (jb + threadIdx.x < n) sj[threadIdx.x] = sel[jb + threadIdx.x];
    __syncthreads();
    u32 m = min(256u, n - jb);
    #pragma unroll 8
    for (u32 j = 0; j < m; ++j) cnt += (u32)(sj[j] > vi);
  }
  if ((u32)i < n && cnt < (u32)PRE) {
    sorted[cnt] = vi;
    if ((u32)(vi >> 32) == 0u)
      atomicOr((unsigned long long*)&invalw[cnt >> 6], 1ULL << (cnt & 63));
  }
}

// ---------------- 5) suppression bitmask: upper-triangle 64x64 tiles (inline gather) --------
__global__ void mask_k(const u64* __restrict__ sorted, const float4* __restrict__ props,
                       u64* __restrict__ mask) {
  #pragma clang fp contract(off)
  __shared__ float4 cb[64];
  int jb = blockIdx.x;
  if (jb < (int)blockIdx.y) return;   // only w >= row-block is ever read
  int i = blockIdx.y * 64 + threadIdx.x;
  int jj = jb * 64 + threadIdx.x;
  float4 cc = make_float4(0.f, 0.f, 0.f, 0.f);
  if (jj < PRE) {
    u64 v = sorted[jj];
    cc = props[0xFFFFu - ((u32)v & 0xFFFFu)];
  }
  cb[threadIdx.x] = cc;
  __syncthreads();
  if (i >= PRE) return;
  u64 vi = sorted[i];
  float4 b = props[0xFFFFu - ((u32)vi & 0xFFFFu)];
  float ai = (b.z - b.x + 1.0f) * (b.w - b.y + 1.0f);
  u64 bits = 0ULL;
  int jmax = min(64, PRE - jb * 64);
  for (int j = 0; j < jmax; ++j) {
    float4 c = cb[j];
    float aj = (c.z - c.x + 1.0f) * (c.w - c.y + 1.0f);
    float iw = fmaxf(fminf(b.z, c.z) - fmaxf(b.x, c.x) + 1.0f, 0.0f);
    float ih = fmaxf(fminf(b.w, c.w) - fmaxf(b.y, c.y) + 1.0f, 0.0f);
    float inter = iw * ih;
    float iou = inter / (ai + aj - inter);
    bits |= ((u64)(iou > 0.7f)) << j;
  }
  mask[(size_t)i * NWORDS + jb] = bits;
}

// ---------------- 6) block-parallel greedy scan with suppressed-row load skipping ----------
__device__ __forceinline__ u64 rl64(u64 v, int lane) {
  u32 lo = (u32)__builtin_amdgcn_readlane((int)(u32)v, lane);
  u32 hi = (u32)__builtin_amdgcn_readlane((int)(u32)(v >> 32), lane);
  return ((u64)hi << 32) | (u64)lo;
}
__device__ __forceinline__ u64 rfl64(u64 v) {
  u32 lo = (u32)__builtin_amdgcn_readfirstlane((int)(u32)v);
  u32 hi = (u32)__builtin_amdgcn_readfirstlane((int)(u32)(v >> 32));
  return ((u64)hi << 32) | (u64)lo;
}

__global__ void __launch_bounds__(1024) nms_scan_k(const u64* __restrict__ mask,
                                                   const u64* __restrict__ invalw,
                                                   u64* __restrict__ keepw) {
  __shared__ u64 Lrem[NWORDS];
  __shared__ u64 Ldiag[64];
  __shared__ u64 Lkeep;
  __shared__ int Lstop;
  __shared__ int Llast;
  const int t = threadIdx.x;
  const int g = t >> 7;                 // 8 groups of 128 threads
  const int w = t & 127;                // word owned (if < 94)
  const bool loader = (w < NWORDS);
  if (t < NWORDS) Lrem[t] = invalw[t];
  if (t == 0) { Lstop = 0; Llast = NWORDS - 1; }
  u64 rv = 0;                           // group-partial remv for word w
  u64 B0[8], B1[8], B2[8];
  int kept = 0;
  __syncthreads();                      // Lrem init visible for predicated ISSUE

// predicated load: skip rows whose suppress bit is already visible in Lrem[bb]
// (invalid-from-start, plus early-published suppressions >= 3 steps old).
#define ISSUE(bb, BUF) \
  if ((bb) < NWORDS && loader) { \
    u64 st_ = Lrem[(bb)]; \
    const int row0_ = (bb) * 64 + g * 8; \
    const u64* pp_ = mask + (size_t)row0_ * NWORDS + w; \
    _Pragma("unroll") \
    for (int j = 0; j < 8; ++j) { \
      bool ok_ = (w >= (bb)) && (row0_ + j < PRE) && !((st_ >> (g * 8 + j)) & 1ULL); \
      BUF[j] = ok_ ? pp_[(size_t)j * NWORDS] : 0ULL; \
    } \
  }

#define STEP(bb, BUF) { \
    if (w == (bb)) {                     /* final publish for word bb */ \
      atomicOr((u32*)&Lrem[(bb)], (u32)rv); \
      atomicOr(((u32*)&Lrem[(bb)]) + 1, (u32)(rv >> 32)); \
      _Pragma("unroll") \
      for (int j = 0; j < 8; ++j) Ldiag[g * 8 + j] = BUF[j]; \
    } \
    if ((bb) + 3 < NWORDS && w == (bb) + 3) {  /* early partial publish (prefetch hint) */ \
      atomicOr((u32*)&Lrem[(bb) + 3], (u32)rv); \
      atomicOr(((u32*)&Lrem[(bb) + 3]) + 1, (u32)(rv >> 32)); \
    } \
    __syncthreads();                     /* X: diag + Lrem[bb] (+hints) visible */ \
    if (t < 64) { \
      u64 dgl = Ldiag[t]; \
      u64 avail = ~rfl64(Lrem[(bb)]);    /* keepable rows in this word */ \
      u64 kb = 0; \
      while (avail) { \
        int i_ = __builtin_ctzll(avail); \
        kb |= 1ULL << i_; \
        u64 di_ = rl64(dgl, i_); \
        avail &= ~di_ & ~((2ULL << i_) - 1ULL); /* 2<<63 wraps to 0 -> ~(-1)=0 */ \
      } \
      if (t == 0) { \
        keepw[(bb)] = kb; \
        Lkeep = kb; \
        kept += (int)__popcll(kb); \
        if (kept >= POST) { Lstop = 1; Llast = (bb); } \
      } \
    } \
    __syncthreads();                     /* Y: kb + stop visible */ \
    { \
      u64 kb_ = Lkeep; \
      const int base_ = g * 8; \
      _Pragma("unroll") \
      for (int j = 0; j < 8; ++j) { \
        u64 k_ = (kb_ >> (base_ + j)) & 1ULL; \
        rv |= (0ULL - k_) & BUF[j]; \
      } \
    } \
    ISSUE((bb) + 3, BUF)                 /* refill this buffer for step bb+3 */ \
    if (Lstop) break; }

  ISSUE(0, B0)
  ISSUE(1, B1)
  ISSUE(2, B2)
  for (int bb = 0; bb < NWORDS; bb += 3) {
    STEP(bb, B0)
    if (bb + 1 < NWORDS) STEP(bb + 1, B1)
    if (bb + 2 < NWORDS) STEP(bb + 2, B2)
  }
#undef ISSUE
#undef STEP

  __syncthreads();                       // Llast final
  int last = Llast;
  for (int w2 = t; w2 < NWORDS; w2 += 1024)
    if (w2 > last) keepw[w2] = 0ULL;
}

// ---------------- 7) zero d_out + rank + scatter outputs ----------------
__global__ void outscatter_k(const u64* __restrict__ keepw, const u64* __restrict__ sorted,
                             const float4* __restrict__ props, float* __restrict__ out) {
  __shared__ u64 wl[NWORDS];
  __shared__ u32 pre[NWORDS];
  int t = threadIdx.x;
  for (int i = t; i < 12000; i += 1024) out[i] = 0.0f;   // blob + scores zero-fill
  if (t < NWORDS) wl[t] = keepw[t];
  __syncthreads();
  if (t == 0) {
    u32 run = 0;
    for (int w = 0; w < NWORDS; ++w) { pre[w] = run; run += (u32)__popcll(wl[w]); }
  }
  __syncthreads();
  for (int i = t; i < PRE; i += 1024) {
    int w = i >> 6;
    u64 word = wl[w];
    if ((word >> (i & 63)) & 1ULL) {
      u32 rank = pre[w] + (u32)__popcll(word & ((1ULL << (i & 63)) - 1ULL));
      if (rank < POST) {
        u64 v = sorted[i];
        float4 b = props[0xFFFFu - ((u32)v & 0xFFFFu)];
        out[rank * 5 + 1] = b.x;
        out[rank * 5 + 2] = b.y;
        out[rank * 5 + 3] = b.z;
        out[rank * 5 + 4] = b.w;
        out[10000 + rank] = __uint_as_float((u32)(v >> 32) & 0x7FFFFFFFu);  // col 0 stays 0
      }
    }
  }
}

extern "C" void kernel_launch(void* const* d_in, const int* in_sizes, int n_in,
                              void* d_out, int out_size, void* d_ws, size_t ws_size,
                              hipStream_t stream) {
  const float* deltas = (const float*)d_in[0];
  const float* scores = (const float*)d_in[1];
  const int* imw = (const int*)d_in[2];
  const int* imh = (const int*)d_in[3];
  char* ws = (char*)d_ws;

  float4* props   = (float4*)(ws + OFF_PROPS);
  u64*    svals   = (u64*)(ws + OFF_SV);
  u64*    sorted  = (u64*)(ws + OFF_SORTED);
  u64*    sel     = (u64*)(ws + OFF_SEL);
  u64*    maskb   = (u64*)(ws + OFF_MASK);
  u32*    ctrl    = (u32*)(ws + OFF_CTRL);
  u32*    h1      = (u32*)(ws + OFF_H1);
  u64*    invalw  = (u64*)(ws + OFF_INVALW);
  u64*    keepw   = (u64*)(ws + OFF_KEEPW);

  hipMemsetAsync(ws + OFF_CTRL, 0, ZERO_BYTES, stream);   // ctrl + h1 + invalw

  decode_k<<<144, 256, 0, stream>>>(deltas, scores, imw, imh, props, svals, h1);
  scan_k<<<1, 64, 0, stream>>>(h1, ctrl);
  compact_k<<<144, 256, 0, stream>>>(svals, ctrl, sel);
  rank_k<<<144, 256, 0, stream>>>(sel, ctrl, sorted, invalw);

  dim3 mgrid(NWORDS, NWORDS);
  mask_k<<<mgrid, 64, 0, stream>>>(sorted, props, maskb);

  nms_scan_k<<<1, 1024, 0, stream>>>(maskb, invalw, keepw);
  outscatter_k<<<1, 1024, 0, stream>>>(keepw, sorted, props, (float*)d_out);
}